// Round 9
// baseline (938.030 us; speedup 1.0000x reference)
//
#include <hip/hip_runtime.h>
#include <hip/hip_bf16.h>

#define NCELL 64
#define CIN 8
#define EE 4
#define DD 4
#define HH 256
#define WW 256

#define EBH 16
#define NBH 13
#define NBANDS_E (HH / EBH)              // 16
#define NBANDS_N ((HH + NBH - 1) / NBH)  // 20
#define NSTRIP 5                         // 5 strips x 60 payload cols

// float4 indices into constant weight table CW
#define DOWN4 0     // [ci=0..7] -> 4 out
#define E14   8     // [ci*9 + dy*3 + dx], 36
#define E24   44
#define UP4   80    // [e=0..3]
#define N14   84    // [ci12*9 + dy*3 + dx], 108
#define N24   192
#define R4    228   // [ci=0..7]
#define B4    236   // bdn, be1, be2, bup, bn1, bn2r
#define CW4_TOTAL 242

__constant__ __align__(16) float CW[CW4_TOTAL * 4];

#define CWF4(i) (reinterpret_cast<const float4*>(CW)[(i)])
#define COMP(v,i) ((i)==0?(v).x:(i)==1?(v).y:(i)==2?(v).z:(v).w)

__device__ __forceinline__ float4 f4z() { return make_float4(0.f, 0.f, 0.f, 0.f); }
__device__ __forceinline__ float silu1(float v) { return v / (1.0f + __expf(-v)); }
__device__ __forceinline__ float4 silu4(float4 v) {
    return make_float4(silu1(v.x), silu1(v.y), silu1(v.z), silu1(v.w));
}
__device__ __forceinline__ float4 shfL(float4 v) {   // value from lane-1
    return make_float4(__shfl_up(v.x, 1), __shfl_up(v.y, 1),
                       __shfl_up(v.z, 1), __shfl_up(v.w, 1));
}
__device__ __forceinline__ float4 shfR(float4 v) {   // value from lane+1
    return make_float4(__shfl_down(v.x, 1), __shfl_down(v.y, 1),
                       __shfl_down(v.z, 1), __shfl_down(v.w, 1));
}
__device__ __forceinline__ void fma4(float4& a, float s, float4 w) {
    a.x = fmaf(s, w.x, a.x);
    a.y = fmaf(s, w.y, a.y);
    a.z = fmaf(s, w.z, a.z);
    a.w = fmaf(s, w.w, a.w);
}

// 3x3 conv accumulate, one 4-ch input group. L/C/R = rows dy=0..2 at cols x-1,x,x+1.
// base4: compile-time float4 index of this group's [ci][dy][dx] weight block.
__device__ __forceinline__ void conv_group(const float4* L, const float4* C, const float4* R,
                                           int base4, float4& acc) {
#pragma unroll
    for (int dy = 0; dy < 3; ++dy) {
#pragma unroll
        for (int ci = 0; ci < 4; ++ci) {
            const int b = base4 + ci * 9 + dy * 3;
            fma4(acc, COMP(L[dy], ci), CWF4(b + 0));
            fma4(acc, COMP(C[dy], ci), CWF4(b + 1));
            fma4(acc, COMP(R[dy], ci), CWF4(b + 2));
        }
    }
}

// transpose all weights into [tap][4-out-channel] float4 table (written to CW symbol)
__global__ __launch_bounds__(128) void prep_kernel(
    const float* __restrict__ wd, const float* __restrict__ bd,
    const float* __restrict__ we1, const float* __restrict__ be1,
    const float* __restrict__ we2, const float* __restrict__ be2,
    const float* __restrict__ wu, const float* __restrict__ bu,
    const float* __restrict__ wn1, const float* __restrict__ bn1,
    const float* __restrict__ wn2, const float* __restrict__ bn2,
    const float* __restrict__ wr, const float* __restrict__ br,
    float4* __restrict__ cw)
{
    const int t = threadIdx.x;
    if (t < 8)   cw[DOWN4 + t] = make_float4(wd[t], wd[8 + t], wd[16 + t], wd[24 + t]);
    if (t < 36)  cw[E14 + t]   = make_float4(we1[t], we1[36 + t], we1[72 + t], we1[108 + t]);
    if (t < 36)  cw[E24 + t]   = make_float4(we2[t], we2[36 + t], we2[72 + t], we2[108 + t]);
    if (t < 4)   cw[UP4 + t]   = make_float4(wu[t], wu[4 + t], wu[8 + t], wu[12 + t]);
    if (t < 108) cw[N14 + t]   = make_float4(wn1[t], wn1[108 + t], wn1[216 + t], wn1[324 + t]);
    if (t < 36)  cw[N24 + t]   = make_float4(wn2[t], wn2[36 + t], wn2[72 + t], wn2[108 + t]);
    if (t < 8)   cw[R4 + t]    = make_float4(wr[t], wr[8 + t], wr[16 + t], wr[24 + t]);
    if (t == 0) {
        cw[B4 + 0] = make_float4(bd[0], bd[1], bd[2], bd[3]);
        cw[B4 + 1] = make_float4(be1[0], be1[1], be1[2], be1[3]);
        cw[B4 + 2] = make_float4(be2[0], be2[1], be2[2], be2[3]);
        cw[B4 + 3] = make_float4(bu[0], bu[1], bu[2], bu[3]);
        cw[B4 + 4] = make_float4(bn1[0], bn1[1], bn1[2], bn1[3]);
        cw[B4 + 5] = make_float4(bn2[0] + br[0], bn2[1] + br[1],
                                 bn2[2] + br[2], bn2[3] + br[3]);
    }
}

// ---------------- edge pass: one wave per (band, strip, cell), registers only ----
__global__ __launch_bounds__(256) void edge_kernel(
    const float* __restrict__ x, float4* __restrict__ P)
{
    const int lane = threadIdx.x & 63;
    const int wv = threadIdx.x >> 6;
    const int y0 = blockIdx.x * EBH;
    const int s = blockIdx.y;
    const int n = blockIdx.z * 4 + wv;
    const int cx = s * 60 + lane - 2;
    const bool colok = (unsigned)cx < (unsigned)WW;
    const bool payload = (lane >= 2) && (lane < 62) && colok;
    const float* __restrict__ xn = x + (size_t)n * CIN * HH * WW;

    const float4 bdn = CWF4(B4 + 0);
    const float4 be1 = CWF4(B4 + 1);
    const float4 be2 = CWF4(B4 + 2);

    float4 za0 = f4z(), za1 = f4z(), za2 = f4z();   // z rows, own col
    float4 zb0 = f4z(), zb1 = f4z(), zb2 = f4z();   // left col
    float4 zc0 = f4z(), zc1 = f4z(), zc2 = f4z();   // right col
    float4 ha0 = f4z(), ha1 = f4z(), ha2 = f4z();   // h1 rows
    float4 hb0 = f4z(), hb1 = f4z(), hb2 = f4z();
    float4 hc0 = f4z(), hc1 = f4z(), hc2 = f4z();

    for (int k = 0; k < EBH + 4; ++k) {
        const int zr = y0 - 2 + k;

        // ---- stage z(zr) = 1x1 down conv ----
        float4 zn = f4z();
        if ((unsigned)zr < (unsigned)HH && colok) {
            zn = bdn;
#pragma unroll
            for (int i = 0; i < CIN; ++i)
                fma4(zn, xn[((size_t)i * HH + zr) * WW + cx], CWF4(DOWN4 + i));
        }
        za0 = za1; za1 = za2; za2 = zn;
        zb0 = zb1; zb1 = zb2; zb2 = shfL(zn);
        zc0 = zc1; zc1 = zc2; zc2 = shfR(zn);

        // ---- h1(zr-1) = silu(3x3 e1) ----
        if (k >= 2) {
            float4 acc = be1;
            {
                float4 L[3] = { zb0, zb1, zb2 };
                float4 C[3] = { za0, za1, za2 };
                float4 R[3] = { zc0, zc1, zc2 };
                conv_group(L, C, R, E14, acc);
            }
            const int hr = zr - 1;
            const float4 hn = ((unsigned)hr < (unsigned)HH && colok) ? silu4(acc) : f4z();
            ha0 = ha1; ha1 = ha2; ha2 = hn;
            hb0 = hb1; hb1 = hb2; hb2 = shfL(hn);
            hc0 = hc1; hc1 = hc2; hc2 = shfR(hn);
        }

        // ---- h2(zr-2) = silu(3x3 e2), write per-cell partial ----
        if (k >= 4) {
            float4 acc = be2;
            {
                float4 L[3] = { hb0, hb1, hb2 };
                float4 C[3] = { ha0, ha1, ha2 };
                float4 R[3] = { hc0, hc1, hc2 };
                conv_group(L, C, R, E24, acc);
            }
            if (payload) {
                const int orow = zr - 2;
                P[(size_t)n * (HH * WW) + orow * WW + cx] = silu4(acc);
            }
        }
    }
}

// ---------------- reduce over cells: A = sum_n P[n] ----------------
__global__ __launch_bounds__(256) void reduce_kernel(
    const float4* __restrict__ P, float4* __restrict__ A4)
{
    __shared__ float4 buf[256];
    const int tid = threadIdx.x;
    const int pix = blockIdx.x * 64 + (tid & 63);
    const int c0 = (tid >> 6) * 16;           // 16-cell chunk per thread
    float4 a = f4z(), b = f4z();
#pragma unroll
    for (int j = 0; j < 16; j += 2) {
        const float4 v0 = P[(size_t)(c0 + j + 0) * (HH * WW) + pix];
        const float4 v1 = P[(size_t)(c0 + j + 1) * (HH * WW) + pix];
        a.x += v0.x; a.y += v0.y; a.z += v0.z; a.w += v0.w;
        b.x += v1.x; b.y += v1.y; b.z += v1.z; b.w += v1.w;
    }
    buf[tid] = make_float4(a.x + b.x, a.y + b.y, a.z + b.z, a.w + b.w);
    __syncthreads();
    if (tid < 64) {
        const float4 p0 = buf[tid], p1 = buf[tid + 64], p2 = buf[tid + 128], p3 = buf[tid + 192];
        A4[blockIdx.x * 64 + tid] =
            make_float4(p0.x + p1.x + p2.x + p3.x, p0.y + p1.y + p2.y + p3.y,
                        p0.z + p1.z + p2.z + p3.z, p0.w + p1.w + p2.w + p3.w);
    }
}

// ---------------- node pass: one wave per (band, strip, cell) ----------------
__global__ __launch_bounds__(256) void node_kernel(
    const float* __restrict__ x, const float* __restrict__ A,
    float* __restrict__ out)
{
    const int lane = threadIdx.x & 63;
    const int wv = threadIdx.x >> 6;
    const int y0 = blockIdx.x * NBH;
    const int h = min(NBH, HH - y0);
    const int s = blockIdx.y;
    const int n = blockIdx.z * 4 + wv;
    const int cx = s * 60 + lane - 2;
    const bool colok = (unsigned)cx < (unsigned)WW;
    const bool payload = (lane >= 2) && (lane < 62) && colok;
    const float* __restrict__ xn = x + (size_t)n * CIN * HH * WW;
    const float4* __restrict__ A4 = reinterpret_cast<const float4*>(A);

    const float4 bup = CWF4(B4 + 3);
    const float4 bn1 = CWF4(B4 + 4);
    const float4 bn2r = CWF4(B4 + 5);

    float4 sa[3][3];   // [group][row] own-col S rows; static-indexed only
#pragma unroll
    for (int g = 0; g < 3; ++g) { sa[g][0] = f4z(); sa[g][1] = f4z(); sa[g][2] = f4z(); }
    float4 ya[3] = { f4z(), f4z(), f4z() };   // y1 rows own
    float4 yb[3] = { f4z(), f4z(), f4z() };   // left
    float4 yc[3] = { f4z(), f4z(), f4z() };   // right

    for (int k = 0; k < h + 4; ++k) {
        const int zr = y0 - 2 + k;

        // ---- stage S(zr) = [x(2 groups) || up(A)] ----
        float4 Sn0 = f4z(), Sn1 = f4z(), Sn2 = f4z();
        if ((unsigned)zr < (unsigned)HH && colok) {
            float xv[CIN];
#pragma unroll
            for (int i = 0; i < CIN; ++i) xv[i] = xn[((size_t)i * HH + zr) * WW + cx];
            Sn0 = make_float4(xv[0], xv[1], xv[2], xv[3]);
            Sn1 = make_float4(xv[4], xv[5], xv[6], xv[7]);
            const float4 a4 = A4[zr * WW + cx];
            Sn2 = bup;
#pragma unroll
            for (int e = 0; e < 4; ++e)
                fma4(Sn2, COMP(a4, e), CWF4(UP4 + e));
        }
        sa[0][0] = sa[0][1]; sa[0][1] = sa[0][2]; sa[0][2] = Sn0;
        sa[1][0] = sa[1][1]; sa[1][1] = sa[1][2]; sa[1][2] = Sn1;
        sa[2][0] = sa[2][1]; sa[2][1] = sa[2][2]; sa[2][2] = Sn2;

        // ---- y1(zr-1) = silu(3x3 n1, 12ch->4ch) ----
        if (k >= 2) {
            float4 acc = bn1;
#pragma unroll
            for (int g = 0; g < 3; ++g) {
                float4 L[3] = { shfL(sa[g][0]), shfL(sa[g][1]), shfL(sa[g][2]) };
                float4 R[3] = { shfR(sa[g][0]), shfR(sa[g][1]), shfR(sa[g][2]) };
                conv_group(L, sa[g], R, N14 + g * 36, acc);
            }
            const int hr = zr - 1;
            const float4 yn = ((unsigned)hr < (unsigned)HH && colok) ? silu4(acc) : f4z();
            ya[0] = ya[1]; ya[1] = ya[2]; ya[2] = yn;
            yb[0] = yb[1]; yb[1] = yb[2]; yb[2] = shfL(yn);
            yc[0] = yc[1]; yc[1] = yc[2]; yc[2] = shfR(yn);
        }

        // ---- out(zr-2) = 3x3 n2 (y1) + 1x1 r (x) ----
        if (k >= 4) {
            float4 acc = bn2r;
            conv_group(yb, ya, yc, N24, acc);
            // residual 1x1 on x: S row (zr-2) own col = sa[0][0], sa[1][0]
#pragma unroll
            for (int ci = 0; ci < 4; ++ci) {
                fma4(acc, COMP(sa[0][0], ci), CWF4(R4 + ci));
                fma4(acc, COMP(sa[1][0], ci), CWF4(R4 + 4 + ci));
            }
            if (payload) {
                const int orow = zr - 2;
                out[(((size_t)n * DD + 0) * HH + orow) * WW + cx] = acc.x;
                out[(((size_t)n * DD + 1) * HH + orow) * WW + cx] = acc.y;
                out[(((size_t)n * DD + 2) * HH + orow) * WW + cx] = acc.z;
                out[(((size_t)n * DD + 3) * HH + orow) * WW + cx] = acc.w;
            }
        }
    }
}

extern "C" void kernel_launch(void* const* d_in, const int* in_sizes, int n_in,
                              void* d_out, int out_size, void* d_ws, size_t ws_size,
                              hipStream_t stream) {
    const float* x      = (const float*)d_in[0];
    const float* w_down = (const float*)d_in[1];
    const float* b_down = (const float*)d_in[2];
    const float* w_e1   = (const float*)d_in[3];
    const float* b_e1   = (const float*)d_in[4];
    const float* w_e2   = (const float*)d_in[5];
    const float* b_e2   = (const float*)d_in[6];
    const float* w_up   = (const float*)d_in[7];
    const float* b_up   = (const float*)d_in[8];
    const float* w_n1   = (const float*)d_in[9];
    const float* b_n1   = (const float*)d_in[10];
    const float* w_n2   = (const float*)d_in[11];
    const float* b_n2   = (const float*)d_in[12];
    const float* w_r    = (const float*)d_in[13];
    const float* b_r    = (const float*)d_in[14];
    float* out = (float*)d_out;

    // Per-cell edge partials exactly fill d_out; node overwrites d_out afterwards.
    float4* P = (float4*)d_out;
    float* A  = (float*)d_ws;   // 1 MiB pixel-major aggregate

    void* cwp = nullptr;
    (void)hipGetSymbolAddress(&cwp, HIP_SYMBOL(CW));

    prep_kernel<<<dim3(1), dim3(128), 0, stream>>>(
        w_down, b_down, w_e1, b_e1, w_e2, b_e2, w_up, b_up,
        w_n1, b_n1, w_n2, b_n2, w_r, b_r, (float4*)cwp);

    edge_kernel<<<dim3(NBANDS_E, NSTRIP, NCELL / 4), dim3(256), 0, stream>>>(x, P);

    reduce_kernel<<<dim3(HH * WW / 64), dim3(256), 0, stream>>>(P, (float4*)A);

    node_kernel<<<dim3(NBANDS_N, NSTRIP, NCELL / 4), dim3(256), 0, stream>>>(x, A, out);
}